// Round 2
// baseline (658.834 us; speedup 1.0000x reference)
//
#include <hip/hip_runtime.h>
#include <math.h>

#define BATCH  8
#define SEQLEN 4096
#define HID    1024
#define STATE  64
#define NC     32
#define TC     (SEQLEN / NC)   // 128 steps per chunk
#define NS     32              // states per lane (2 lanes per channel)
#define NP     16              // float2 pairs per lane

typedef float f32x2 __attribute__((ext_vector_type(2)));

// ws layout (bytes):
//   pa: [0, 256K)  pw: [256K, 512K)  pE: [512K, 768K)
//   zl: [1M, 1M + (NC-1)*BATCH*HID*STATE*4)  = 62 MB of chunk states
#define WS_PA 0
#define WS_PW (256 * 1024)
#define WS_PE (512 * 1024)
#define WS_ZL (1024 * 1024)

// ---------------------------------------------------------------- K0: params
__global__ void k0_params(const float* __restrict__ A, const float* __restrict__ Bm,
                          const float* __restrict__ C, const float* __restrict__ dt,
                          float* __restrict__ pa, float* __restrict__ pw,
                          float* __restrict__ pE) {
    int i = blockIdx.x * 256 + threadIdx.x;
    if (i >= HID * STATE) return;
    int n = i & (STATE - 1);
    float aexp = expf(A[i]);
    float dtn  = dt[n];
    float a    = expf(-aexp * dtn);
    pa[i] = a;
    pw[i] = C[i] * (Bm[i] * (1.0f - a) / aexp);   // C * dB
    pE[i] = expf(-aexp * dtn * (float)TC);        // a^TC (chunk transition)
}

// ------------------------------------------- K1: chunk-local end states (z-space)
__global__ __launch_bounds__(256, 4) void k1_locals(const float* __restrict__ u,
                                                    const float* __restrict__ pa,
                                                    float* __restrict__ zl) {
    int wid  = (blockIdx.x * 256 + threadIdx.x) >> 6;   // wave task id
    int lane = threadIdx.x & 63;
    int dset = wid & 31;
    int b    = (wid >> 5) & 7;
    int c    = wid >> 8;                                // chunk 0..NC-2
    int dl   = lane >> 1, p = lane & 1;
    int d    = dset * 32 + dl;

    f32x2 a2[NP], z2[NP];
    {
        const f32x2* pap = (const f32x2*)(pa + (size_t)d * STATE + p * NS);
        #pragma unroll
        for (int j = 0; j < NP; j++) a2[j] = pap[j];
    }
    #pragma unroll
    for (int j = 0; j < NP; j++) { z2[j].x = 0.f; z2[j].y = 0.f; }

    const float* up = u + ((size_t)b * SEQLEN + (size_t)c * TC) * HID + d;

    float ubuf[8];
    #pragma unroll
    for (int i = 0; i < 8; i++) ubuf[i] = up[(size_t)i * HID];

    for (int t0 = 0; t0 < TC; t0 += 8) {
        float unext[8];
        #pragma unroll
        for (int i = 0; i < 8; i++) {
            int tt = t0 + 8 + i; if (tt > TC - 1) tt = TC - 1;   // safe prefetch
            unext[i] = up[(size_t)tt * HID];
        }
        #pragma unroll
        for (int i = 0; i < 8; i++) {
            f32x2 us; us.x = ubuf[i]; us.y = ubuf[i];
            #pragma unroll
            for (int j = 0; j < NP; j++)
                z2[j] = __builtin_elementwise_fma(a2[j], z2[j], us);
        }
        #pragma unroll
        for (int i = 0; i < 8; i++) ubuf[i] = unext[i];
    }

    f32x2* zp = (f32x2*)(zl + (((size_t)c * BATCH + b) * HID + d) * STATE + p * NS);
    #pragma unroll
    for (int j = 0; j < NP; j++) zp[j] = z2[j];
}

// ---------------------------------- K2: prefix scan over chunks (in-place in zl)
__global__ void k2_scan(const float* __restrict__ pE, float* __restrict__ zl) {
    int i  = blockIdx.x * 256 + threadIdx.x;            // (b,d,n)
    int dn = i & (HID * STATE - 1);
    float E = pE[dn];
    size_t stride = (size_t)BATCH * HID * STATE;
    float g = zl[i];                                     // slot0 already global
    for (int c = 1; c < NC - 1; c++) {
        float v = zl[i + c * stride];
        g = fmaf(E, g, v);
        zl[i + c * stride] = g;                          // slot c = global end of chunk c
    }
}

// --------------------------------------------------- K3: main pass with outputs
__global__ __launch_bounds__(256, 4) void k3_main(const float* __restrict__ u,
                                                  const float* __restrict__ Dv,
                                                  const float* __restrict__ pa,
                                                  const float* __restrict__ pw,
                                                  const float* __restrict__ zl,
                                                  float* __restrict__ out) {
    int wid  = (blockIdx.x * 256 + threadIdx.x) >> 6;
    int lane = threadIdx.x & 63;
    int dset = wid & 31;
    int b    = (wid >> 5) & 7;
    int c    = wid >> 8;                                // chunk 0..NC-1
    int dl   = lane >> 1, p = lane & 1;
    int d    = dset * 32 + dl;

    f32x2 a2[NP], w2[NP], z2[NP];
    {
        const f32x2* pap = (const f32x2*)(pa + (size_t)d * STATE + p * NS);
        const f32x2* pwp = (const f32x2*)(pw + (size_t)d * STATE + p * NS);
        #pragma unroll
        for (int j = 0; j < NP; j++) { a2[j] = pap[j]; w2[j] = pwp[j]; }
    }
    if (c == 0) {
        #pragma unroll
        for (int j = 0; j < NP; j++) { z2[j].x = 0.f; z2[j].y = 0.f; }
    } else {
        size_t stride = (size_t)BATCH * HID * STATE;
        const f32x2* zp = (const f32x2*)(zl + (size_t)(c - 1) * stride +
                                         ((size_t)b * HID + d) * STATE + p * NS);
        #pragma unroll
        for (int j = 0; j < NP; j++) z2[j] = zp[j];
    }

    float dvd = Dv[d];
    const float* up = u   + ((size_t)b * SEQLEN + (size_t)c * TC) * HID + d;
    float*       po = out + ((size_t)b * SEQLEN + (size_t)c * TC) * HID + d;

    float ubuf[8];
    #pragma unroll
    for (int i = 0; i < 8; i++) ubuf[i] = up[(size_t)i * HID];

    for (int t0 = 0; t0 < TC; t0 += 8) {
        float unext[8];
        #pragma unroll
        for (int i = 0; i < 8; i++) {
            int tt = t0 + 8 + i; if (tt > TC - 1) tt = TC - 1;
            unext[i] = up[(size_t)tt * HID];
        }
        #pragma unroll
        for (int i = 0; i < 8; i++) {
            f32x2 us; us.x = ubuf[i]; us.y = ubuf[i];
            #pragma unroll
            for (int j = 0; j < NP; j++)
                z2[j] = __builtin_elementwise_fma(a2[j], z2[j], us);
            // dot product: 4 independent accumulator chains (depth 4), then combine
            f32x2 acc0 = z2[0] * w2[0];
            f32x2 acc1 = z2[1] * w2[1];
            f32x2 acc2 = z2[2] * w2[2];
            f32x2 acc3 = z2[3] * w2[3];
            #pragma unroll
            for (int j = 4; j < NP; j += 4) {
                acc0 = __builtin_elementwise_fma(z2[j + 0], w2[j + 0], acc0);
                acc1 = __builtin_elementwise_fma(z2[j + 1], w2[j + 1], acc1);
                acc2 = __builtin_elementwise_fma(z2[j + 2], w2[j + 2], acc2);
                acc3 = __builtin_elementwise_fma(z2[j + 3], w2[j + 3], acc3);
            }
            acc0 += acc1;
            acc2 += acc3;
            acc0 += acc2;
            float y = acc0.x + acc0.y;
            y += __shfl_xor(y, 1);                       // sum the 2 lanes of this channel
            y = fmaf(dvd, ubuf[i], y);
            po[(size_t)(t0 + i) * HID] = y;              // both lanes store same value
        }
        #pragma unroll
        for (int i = 0; i < 8; i++) ubuf[i] = unext[i];
    }
}

extern "C" void kernel_launch(void* const* d_in, const int* in_sizes, int n_in,
                              void* d_out, int out_size, void* d_ws, size_t ws_size,
                              hipStream_t stream) {
    const float* u  = (const float*)d_in[0];
    const float* A  = (const float*)d_in[1];
    const float* Bm = (const float*)d_in[2];
    const float* C  = (const float*)d_in[3];
    const float* Dv = (const float*)d_in[4];
    const float* dt = (const float*)d_in[5];
    float* out = (float*)d_out;

    char* ws = (char*)d_ws;
    float* pa = (float*)(ws + WS_PA);
    float* pw = (float*)(ws + WS_PW);
    float* pE = (float*)(ws + WS_PE);
    float* zl = (float*)(ws + WS_ZL);

    k0_params<<<(HID * STATE) / 256, 256, 0, stream>>>(A, Bm, C, dt, pa, pw, pE);
    k1_locals<<<(8 * 32 * (NC - 1) * 64) / 256, 256, 0, stream>>>(u, pa, zl);
    k2_scan<<<(BATCH * HID * STATE) / 256, 256, 0, stream>>>(pE, zl);
    k3_main<<<(8 * 32 * NC * 64) / 256, 256, 0, stream>>>(u, Dv, pa, pw, zl, out);
}

// Round 3
// 200.858 us; speedup vs baseline: 3.2801x; 3.2801x over previous
//
#include <hip/hip_runtime.h>
#include <math.h>

#define BATCH  8
#define SEQLEN 4096
#define HID    1024
#define STATE  64
#define NC     16
#define TC     (SEQLEN / NC)   // 256 steps per chunk
#define NS     32              // states per lane (2 lanes per channel)
#define NP     16              // float2 pairs per lane
#define TG     16              // time-group / prefetch depth

typedef float f32x2 __attribute__((ext_vector_type(2)));

// ws layout (bytes):
//   pa: [0, 256K)  pw: [256K, 512K)  pE: [512K, 768K)
//   zl: [1M, 1M + (NC-1)*BATCH*HID*STATE*4)  = 30 MB of chunk states
#define WS_PA 0
#define WS_PW (256 * 1024)
#define WS_PE (512 * 1024)
#define WS_ZL (1024 * 1024)

// ---------------------------------------------------------------- K0: params
__global__ void k0_params(const float* __restrict__ A, const float* __restrict__ Bm,
                          const float* __restrict__ C, const float* __restrict__ dt,
                          float* __restrict__ pa, float* __restrict__ pw,
                          float* __restrict__ pE) {
    int i = blockIdx.x * 256 + threadIdx.x;
    if (i >= HID * STATE) return;
    int n = i & (STATE - 1);
    float aexp = expf(A[i]);
    float dtn  = dt[n];
    float a    = expf(-aexp * dtn);
    pa[i] = a;
    pw[i] = C[i] * (Bm[i] * (1.0f - a) / aexp);   // C * dB
    pE[i] = expf(-aexp * dtn * (float)TC);        // a^TC (chunk transition)
}

// ------------------------------------------- K1: chunk-local end states (z-space)
__global__ __launch_bounds__(256, 4) void k1_locals(const float* __restrict__ u,
                                                    const float* __restrict__ pa,
                                                    float* __restrict__ zl) {
    int wid  = (blockIdx.x * 256 + threadIdx.x) >> 6;   // wave task id
    int lane = threadIdx.x & 63;
    int dset = wid & 31;
    int b    = (wid >> 5) & 7;
    int c    = wid >> 8;                                // chunk 0..NC-2
    int dl   = lane >> 1, p = lane & 1;
    int d    = dset * 32 + dl;

    f32x2 a2[NP], z2[NP];
    {
        const f32x2* pap = (const f32x2*)(pa + (size_t)d * STATE + p * NS);
        #pragma unroll
        for (int j = 0; j < NP; j++) a2[j] = pap[j];
    }
    #pragma unroll
    for (int j = 0; j < NP; j++) { z2[j].x = 0.f; z2[j].y = 0.f; }

    const float* up = u + ((size_t)b * SEQLEN + (size_t)c * TC) * HID + d;

    float ubuf[TG];
    #pragma unroll
    for (int i = 0; i < TG; i++) ubuf[i] = up[(size_t)i * HID];

    for (int t0 = 0; t0 < TC; t0 += TG) {
        float unext[TG];
        #pragma unroll
        for (int i = 0; i < TG; i++) {
            int tt = t0 + TG + i; if (tt > TC - 1) tt = TC - 1;   // safe prefetch
            unext[i] = up[(size_t)tt * HID];
        }
        #pragma unroll
        for (int i = 0; i < TG; i++) {
            f32x2 us; us.x = ubuf[i]; us.y = ubuf[i];
            #pragma unroll
            for (int j = 0; j < NP; j++)
                z2[j] = __builtin_elementwise_fma(a2[j], z2[j], us);
        }
        #pragma unroll
        for (int i = 0; i < TG; i++) ubuf[i] = unext[i];
    }

    f32x2* zp = (f32x2*)(zl + (((size_t)c * BATCH + b) * HID + d) * STATE + p * NS);
    #pragma unroll
    for (int j = 0; j < NP; j++) zp[j] = z2[j];
}

// ---------------------------------- K2: prefix scan over chunks (in-place in zl)
__global__ void k2_scan(const float* __restrict__ pE, float* __restrict__ zl) {
    int i  = blockIdx.x * 256 + threadIdx.x;            // (b,d,n)
    int dn = i & (HID * STATE - 1);
    float E = pE[dn];
    size_t stride = (size_t)BATCH * HID * STATE;
    float g = zl[i];                                     // slot0 already global
    for (int c = 1; c < NC - 1; c++) {
        float v = zl[i + c * stride];
        g = fmaf(E, g, v);
        zl[i + c * stride] = g;                          // slot c = global end of chunk c
    }
}

// --------------------------------------------------- K3: main pass with outputs
__global__ __launch_bounds__(256, 3) void k3_main(const float* __restrict__ u,
                                                  const float* __restrict__ Dv,
                                                  const float* __restrict__ pa,
                                                  const float* __restrict__ pw,
                                                  const float* __restrict__ zl,
                                                  float* __restrict__ out) {
    int wid  = (blockIdx.x * 256 + threadIdx.x) >> 6;
    int lane = threadIdx.x & 63;
    int dset = wid & 31;
    int b    = (wid >> 5) & 7;
    int c    = wid >> 8;                                // chunk 0..NC-1
    int dl   = lane >> 1, p = lane & 1;
    int d    = dset * 32 + dl;

    f32x2 a2[NP], w2[NP], z2[NP];
    {
        const f32x2* pap = (const f32x2*)(pa + (size_t)d * STATE + p * NS);
        const f32x2* pwp = (const f32x2*)(pw + (size_t)d * STATE + p * NS);
        #pragma unroll
        for (int j = 0; j < NP; j++) { a2[j] = pap[j]; w2[j] = pwp[j]; }
    }
    if (c == 0) {
        #pragma unroll
        for (int j = 0; j < NP; j++) { z2[j].x = 0.f; z2[j].y = 0.f; }
    } else {
        size_t stride = (size_t)BATCH * HID * STATE;
        const f32x2* zp = (const f32x2*)(zl + (size_t)(c - 1) * stride +
                                         ((size_t)b * HID + d) * STATE + p * NS);
        #pragma unroll
        for (int j = 0; j < NP; j++) z2[j] = zp[j];
    }

    float dvd = Dv[d];
    const float* up = u   + ((size_t)b * SEQLEN + (size_t)c * TC) * HID + d;
    float*       po = out + ((size_t)b * SEQLEN + (size_t)c * TC) * HID + d;

    float ubuf[TG];
    #pragma unroll
    for (int i = 0; i < TG; i++) ubuf[i] = up[(size_t)i * HID];

    for (int t0 = 0; t0 < TC; t0 += TG) {
        float unext[TG];
        #pragma unroll
        for (int i = 0; i < TG; i++) {
            int tt = t0 + TG + i; if (tt > TC - 1) tt = TC - 1;
            unext[i] = up[(size_t)tt * HID];
        }
        #pragma unroll
        for (int i = 0; i < TG; i++) {
            f32x2 us; us.x = ubuf[i]; us.y = ubuf[i];
            #pragma unroll
            for (int j = 0; j < NP; j++)
                z2[j] = __builtin_elementwise_fma(a2[j], z2[j], us);
            // dot product: 4 independent accumulator chains (depth 4), then combine
            f32x2 acc0 = z2[0] * w2[0];
            f32x2 acc1 = z2[1] * w2[1];
            f32x2 acc2 = z2[2] * w2[2];
            f32x2 acc3 = z2[3] * w2[3];
            #pragma unroll
            for (int j = 4; j < NP; j += 4) {
                acc0 = __builtin_elementwise_fma(z2[j + 0], w2[j + 0], acc0);
                acc1 = __builtin_elementwise_fma(z2[j + 1], w2[j + 1], acc1);
                acc2 = __builtin_elementwise_fma(z2[j + 2], w2[j + 2], acc2);
                acc3 = __builtin_elementwise_fma(z2[j + 3], w2[j + 3], acc3);
            }
            acc0 += acc1;
            acc2 += acc3;
            acc0 += acc2;
            float y = acc0.x + acc0.y;
            y += __shfl_xor(y, 1);                       // sum the 2 lanes of this channel
            y = fmaf(dvd, ubuf[i], y);
            // nontemporal: out is write-once; don't let it evict u from L2/L3
            __builtin_nontemporal_store(y, &po[(size_t)(t0 + i) * HID]);
        }
        #pragma unroll
        for (int i = 0; i < TG; i++) ubuf[i] = unext[i];
    }
}

extern "C" void kernel_launch(void* const* d_in, const int* in_sizes, int n_in,
                              void* d_out, int out_size, void* d_ws, size_t ws_size,
                              hipStream_t stream) {
    const float* u  = (const float*)d_in[0];
    const float* A  = (const float*)d_in[1];
    const float* Bm = (const float*)d_in[2];
    const float* C  = (const float*)d_in[3];
    const float* Dv = (const float*)d_in[4];
    const float* dt = (const float*)d_in[5];
    float* out = (float*)d_out;

    char* ws = (char*)d_ws;
    float* pa = (float*)(ws + WS_PA);
    float* pw = (float*)(ws + WS_PW);
    float* pE = (float*)(ws + WS_PE);
    float* zl = (float*)(ws + WS_ZL);

    k0_params<<<(HID * STATE) / 256, 256, 0, stream>>>(A, Bm, C, dt, pa, pw, pE);
    k1_locals<<<(8 * 32 * (NC - 1) * 64) / 256, 256, 0, stream>>>(u, pa, zl);
    k2_scan<<<(BATCH * HID * STATE) / 256, 256, 0, stream>>>(pE, zl);
    k3_main<<<(8 * 32 * NC * 64) / 256, 256, 0, stream>>>(u, Dv, pa, pw, zl, out);
}

// Round 4
// 186.932 us; speedup vs baseline: 3.5245x; 1.0745x over previous
//
#include <hip/hip_runtime.h>
#include <math.h>

#define BATCH  8
#define SEQLEN 4096
#define HID    1024
#define STATE  64
#define NC     16
#define TC     (SEQLEN / NC)   // 256 steps per chunk
#define LPC    4               // lanes per channel
#define CW     16              // channels per wave (64 / LPC)
#define NS     16              // states per lane (STATE / LPC)
#define NP     8               // f32x2 pairs per lane
#define TG     16              // time-group / prefetch depth

typedef float f32x2 __attribute__((ext_vector_type(2)));

// ws layout (bytes):
//   pa: [0, 256K)  pw: [256K, 512K)  pE: [512K, 768K)
//   zl: [1M, 1M + (NC-1)*BATCH*HID*STATE*4)  = 30 MB of chunk states
#define WS_PA 0
#define WS_PW (256 * 1024)
#define WS_PE (512 * 1024)
#define WS_ZL (1024 * 1024)

// quad-lane sum via DPP (pure VALU; avoids DS shfl + lgkmcnt stall)
__device__ __forceinline__ float quad_reduce_add(float y) {
    int t = __builtin_amdgcn_mov_dpp(__builtin_bit_cast(int, y), 0xB1, 0xF, 0xF, true); // quad_perm [1,0,3,2]
    y += __builtin_bit_cast(float, t);
    t = __builtin_amdgcn_mov_dpp(__builtin_bit_cast(int, y), 0x4E, 0xF, 0xF, true);     // quad_perm [2,3,0,1]
    y += __builtin_bit_cast(float, t);
    return y;
}

// ---------------------------------------------------------------- K0: params
__global__ void k0_params(const float* __restrict__ A, const float* __restrict__ Bm,
                          const float* __restrict__ C, const float* __restrict__ dt,
                          float* __restrict__ pa, float* __restrict__ pw,
                          float* __restrict__ pE) {
    int i = blockIdx.x * 256 + threadIdx.x;
    if (i >= HID * STATE) return;
    int n = i & (STATE - 1);
    float aexp = expf(A[i]);
    float dtn  = dt[n];
    float a    = expf(-aexp * dtn);
    pa[i] = a;
    pw[i] = C[i] * (Bm[i] * (1.0f - a) / aexp);   // C * dB
    pE[i] = expf(-aexp * dtn * (float)TC);        // a^TC (chunk transition)
}

// ------------------------------------------- K1: chunk-local end states (z-space)
__global__ __launch_bounds__(256, 3) void k1_locals(const float* __restrict__ u,
                                                    const float* __restrict__ pa,
                                                    float* __restrict__ zl) {
    int wid  = (blockIdx.x * 256 + threadIdx.x) >> 6;   // wave task id
    int lane = threadIdx.x & 63;
    int dset = wid & 63;
    int b    = (wid >> 6) & 7;
    int c    = wid >> 9;                                // chunk 0..NC-2
    int dl   = lane >> 2, p = lane & 3;
    int d    = dset * CW + dl;

    f32x2 a2[NP], z2[NP];
    {
        const f32x2* pap = (const f32x2*)(pa + (size_t)d * STATE + p * NS);
        #pragma unroll
        for (int j = 0; j < NP; j++) a2[j] = pap[j];
    }
    #pragma unroll
    for (int j = 0; j < NP; j++) { z2[j].x = 0.f; z2[j].y = 0.f; }

    const float* up = u + ((size_t)b * SEQLEN + (size_t)c * TC) * HID + d;

    float ubuf[TG];
    #pragma unroll
    for (int i = 0; i < TG; i++) ubuf[i] = up[(size_t)i * HID];

    for (int t0 = 0; t0 < TC; t0 += TG) {
        int nb = t0 + TG;
        if (nb > TC - TG) nb = TC - TG;                 // wave-uniform clamp
        const float* un = up + (size_t)nb * HID;
        float unext[TG];
        #pragma unroll
        for (int i = 0; i < TG; i++) unext[i] = un[(size_t)i * HID];

        #pragma unroll
        for (int i = 0; i < TG; i++) {
            f32x2 us; us.x = ubuf[i]; us.y = ubuf[i];
            #pragma unroll
            for (int j = 0; j < NP; j++)
                z2[j] = __builtin_elementwise_fma(a2[j], z2[j], us);
        }
        #pragma unroll
        for (int i = 0; i < TG; i++) ubuf[i] = unext[i];
    }

    f32x2* zp = (f32x2*)(zl + (((size_t)c * BATCH + b) * HID + d) * STATE + p * NS);
    #pragma unroll
    for (int j = 0; j < NP; j++) zp[j] = z2[j];
}

// ---------------------------------- K2: prefix scan over chunks (in-place in zl)
__global__ void k2_scan(const float* __restrict__ pE, float* __restrict__ zl) {
    int i  = blockIdx.x * 256 + threadIdx.x;            // (b,d,n)
    int dn = i & (HID * STATE - 1);
    float E = pE[dn];
    size_t stride = (size_t)BATCH * HID * STATE;
    float g = zl[i];                                     // slot0 already global
    for (int c = 1; c < NC - 1; c++) {
        float v = zl[i + c * stride];
        g = fmaf(E, g, v);
        zl[i + c * stride] = g;                          // slot c = global end of chunk c
    }
}

// --------------------------------------------------- K3: main pass with outputs
__global__ __launch_bounds__(256, 3) void k3_main(const float* __restrict__ u,
                                                  const float* __restrict__ Dv,
                                                  const float* __restrict__ pa,
                                                  const float* __restrict__ pw,
                                                  const float* __restrict__ zl,
                                                  float* __restrict__ out) {
    int wid  = (blockIdx.x * 256 + threadIdx.x) >> 6;
    int lane = threadIdx.x & 63;
    int dset = wid & 63;
    int b    = (wid >> 6) & 7;
    int c    = wid >> 9;                                // chunk 0..NC-1
    int dl   = lane >> 2, p = lane & 3;
    int d    = dset * CW + dl;

    f32x2 a2[NP], w2[NP], z2[NP];
    {
        const f32x2* pap = (const f32x2*)(pa + (size_t)d * STATE + p * NS);
        const f32x2* pwp = (const f32x2*)(pw + (size_t)d * STATE + p * NS);
        #pragma unroll
        for (int j = 0; j < NP; j++) { a2[j] = pap[j]; w2[j] = pwp[j]; }
    }
    if (c == 0) {
        #pragma unroll
        for (int j = 0; j < NP; j++) { z2[j].x = 0.f; z2[j].y = 0.f; }
    } else {
        size_t stride = (size_t)BATCH * HID * STATE;
        const f32x2* zp = (const f32x2*)(zl + (size_t)(c - 1) * stride +
                                         ((size_t)b * HID + d) * STATE + p * NS);
        #pragma unroll
        for (int j = 0; j < NP; j++) z2[j] = zp[j];
    }

    float dvd = Dv[d];
    const float* up = u   + ((size_t)b * SEQLEN + (size_t)c * TC) * HID + d;
    float*       po = out + ((size_t)b * SEQLEN + (size_t)c * TC) * HID + d;

    float ubuf[TG];
    #pragma unroll
    for (int i = 0; i < TG; i++) ubuf[i] = up[(size_t)i * HID];

    for (int t0 = 0; t0 < TC; t0 += TG) {
        int nb = t0 + TG;
        if (nb > TC - TG) nb = TC - TG;                 // wave-uniform clamp
        const float* un = up + (size_t)nb * HID;
        float unext[TG];
        #pragma unroll
        for (int i = 0; i < TG; i++) unext[i] = un[(size_t)i * HID];

        #pragma unroll
        for (int i = 0; i < TG; i++) {
            f32x2 us; us.x = ubuf[i]; us.y = ubuf[i];
            #pragma unroll
            for (int j = 0; j < NP; j++)
                z2[j] = __builtin_elementwise_fma(a2[j], z2[j], us);
            // dot over this lane's 16 states: 2 independent chains, then combine
            f32x2 acc0 = z2[0] * w2[0];
            f32x2 acc1 = z2[1] * w2[1];
            #pragma unroll
            for (int j = 2; j < NP; j += 2) {
                acc0 = __builtin_elementwise_fma(z2[j + 0], w2[j + 0], acc0);
                acc1 = __builtin_elementwise_fma(z2[j + 1], w2[j + 1], acc1);
            }
            acc0 += acc1;
            float y = acc0.x + acc0.y;
            y = quad_reduce_add(y);                      // sum the 4 lanes of this channel
            y = fmaf(dvd, ubuf[i], y);
            // nontemporal: out is write-once; don't let it evict u from L2/L3
            __builtin_nontemporal_store(y, &po[(size_t)(t0 + i) * HID]);
        }
        #pragma unroll
        for (int i = 0; i < TG; i++) ubuf[i] = unext[i];
    }
}

extern "C" void kernel_launch(void* const* d_in, const int* in_sizes, int n_in,
                              void* d_out, int out_size, void* d_ws, size_t ws_size,
                              hipStream_t stream) {
    const float* u  = (const float*)d_in[0];
    const float* A  = (const float*)d_in[1];
    const float* Bm = (const float*)d_in[2];
    const float* C  = (const float*)d_in[3];
    const float* Dv = (const float*)d_in[4];
    const float* dt = (const float*)d_in[5];
    float* out = (float*)d_out;

    char* ws = (char*)d_ws;
    float* pa = (float*)(ws + WS_PA);
    float* pw = (float*)(ws + WS_PW);
    float* pE = (float*)(ws + WS_PE);
    float* zl = (float*)(ws + WS_ZL);

    k0_params<<<(HID * STATE) / 256, 256, 0, stream>>>(A, Bm, C, dt, pa, pw, pE);
    // k1: 64 dsets * 8 batches * (NC-1) chunks waves, 4 waves/block
    k1_locals<<<(64 * 8 * (NC - 1)) / 4, 256, 0, stream>>>(u, pa, zl);
    k2_scan<<<(BATCH * HID * STATE) / 256, 256, 0, stream>>>(pE, zl);
    // k3: 64 dsets * 8 batches * NC chunks waves, 4 waves/block
    k3_main<<<(64 * 8 * NC) / 4, 256, 0, stream>>>(u, Dv, pa, pw, zl, out);
}